// Round 5
// baseline (269.531 us; speedup 1.0000x reference)
//
#include <hip/hip_runtime.h>
#include <math.h>

#define T_DIM 64
#define U_DIM 142
#define I_DIM 4500
#define B_DIM 16384
#define K_TOP 10

// Mask geometry: mask[t][i][w], w = 0..4 words of 32 v-bits (142 bits used).
// Size = 64 * 4500 * 5 ints = 5.76 MB (fits aggregate L2, trivially L3).
#define NWPC  5
#define NCH   18                               // 256-item chunks per t
#define MASK_INTS ((size_t)T_DIM * I_DIM * NWPC)
#define WS_BYTES  (MASK_INTS * sizeof(unsigned))

// ---------------------------------------------------------------------------
// Phase 1: coalesced one-shot pass over qos building the rated-bitmask.
// Wave = (t, 256-item chunk, v-word). Lane covers 4 consecutive i via float4.
// Loop body is load + 4 cmp/or into registers: no LDS, no barriers, no
// cross-iteration deps -> compiler software-pipelines the HBM stream.
// v-split is WORD-aligned (32 v's per wave; last wave 14) so each wave owns
// its output word exclusively -> no combining pass.
// ---------------------------------------------------------------------------
__global__ __launch_bounds__(256) void build_mask(
    const float* __restrict__ qos,   // [T,U,I]
    unsigned*    __restrict__ mask)  // [T,I,NWPC]
{
    const int lane = threadIdx.x & 63;
    const int gw   = blockIdx.x * 4 + (threadIdx.x >> 6);  // 0..5759
    const int w    = gw % NWPC;
    const int tc   = gw / NWPC;
    const int c    = tc % NCH;
    const int t    = tc / NCH;

    const int i0 = c * 256 + lane * 4;
    if (i0 + 3 >= I_DIM) return;     // tail chunk: lanes past i=4499 idle

    const int v0 = w * 32;
    const int nv = (w == 4) ? (U_DIM - 128) : 32;   // 14 for the last word

    const float* p = qos + ((size_t)t * U_DIM + v0) * I_DIM + i0;
    unsigned m0 = 0, m1 = 0, m2 = 0, m3 = 0;
#pragma unroll 4
    for (int k = 0; k < nv; ++k, p += I_DIM) {
        const float4 q = *(const float4*)p;       // 16B aligned: i0%4==0, row%4==0
        const unsigned bit = 1u << ((v0 + k) & 31);
        if (q.x > 0.0f) m0 |= bit;
        if (q.y > 0.0f) m1 |= bit;
        if (q.z > 0.0f) m2 |= bit;
        if (q.w > 0.0f) m3 |= bit;
    }
    unsigned* mp = mask + ((size_t)t * I_DIM + i0) * NWPC + w;
    mp[0 * NWPC] = m0;
    mp[1 * NWPC] = m1;
    mp[2 * NWPC] = m2;
    mp[3 * NWPC] = m3;
}

// ---------------------------------------------------------------------------
// Phase 2: one wave per batch. Selection runs entirely on the 142-bit mask
// (20 B, L2/L3-hot) + cached sim/avg rows; qos is touched ONLY for the 10
// winners (one 10-lane load). Selection semantics bit-identical to the
// proven kernel: val = rated ? sim : 0, -INF for v>=142, strict-> lower-v
// tie-break, ssum/wsum accumulated in winner order k=0..9.
// ---------------------------------------------------------------------------
__global__ __launch_bounds__(256) void ucf_select(
    const float*    __restrict__ qos,       // [T,U,I]
    const float*    __restrict__ user_avg,  // [T,U]
    const float*    __restrict__ user_sim,  // [U,U]
    const int*      __restrict__ user_id,   // [B]
    const int*      __restrict__ item_id,   // [B]
    const int*      __restrict__ time_id,   // [B]
    const unsigned* __restrict__ mask,      // [T,I,NWPC]
    float*          __restrict__ out)       // [B]
{
    const int lane = threadIdx.x & 63;
    const int wid  = threadIdx.x >> 6;
    const int b    = blockIdx.x * 4 + wid;
    if (b >= B_DIM) return;

    const int u = user_id[b];
    const int i = item_id[b];
    const int t = time_id[b];

    // 142-bit rated mask for this (t,i): lanes 0..4 load the 5 words.
    const unsigned* mp = mask + ((size_t)t * I_DIM + i) * NWPC;
    const unsigned mw = (lane < NWPC) ? mp[lane] : 0u;

    const float* srow = user_sim + (size_t)u * U_DIM;
    const float* arow = user_avg + (size_t)t * U_DIM;

    // Distribute words: v0=lane -> word lane>>5; v1=lane+64 -> word 2+(lane>>5);
    // v2=lane+128 -> word 4, bit (lane+128)&31 == lane for lane<14.
    const unsigned wA = __shfl(mw, lane >> 5, 64);
    const unsigned wB = __shfl(mw, 2 + (lane >> 5), 64);
    const unsigned wC = __shfl(mw, 4, 64);
    const unsigned bitm = 1u << (lane & 31);

    float val0 = (wA & bitm) ? srow[lane] : 0.0f;
    float val1 = (wB & bitm) ? srow[lane + 64] : 0.0f;
    float val2 = -INFINITY;                       // v>=142 must stay below negatives
    const bool has2 = (lane + 128) < U_DIM;       // lanes 0..13
    if (has2) val2 = (wC & bitm) ? srow[lane + 128] : 0.0f;

    float ssum = 0.0f;
    float wv[K_TOP];
    int   wk[K_TOP];
#pragma unroll
    for (int k = 0; k < K_TOP; ++k) {
        // local argmax over 3 slots (ascending v, strict > keeps lower v on tie)
        float mv = val0; int mk = lane;
        if (val1 > mv) { mv = val1; mk = lane + 64; }
        if (val2 > mv) { mv = val2; mk = lane + 128; }
        // butterfly max-reduce on (val,idx); tie -> lower user index
#pragma unroll
        for (int off = 32; off > 0; off >>= 1) {
            const float ov = __shfl_xor(mv, off, 64);
            const int   ok = __shfl_xor(mk, off, 64);
            if (ov > mv || (ov == mv && ok < mk)) { mv = ov; mk = ok; }
        }
        wv[k] = mv;          // uniform across lanes
        wk[k] = mk;          // uniform across lanes
        ssum += mv;          // same accumulation order as proven kernel
        // winner's owner lane removes it from candidacy
        const int sl = mk >> 6;
        const int wl = mk & 63;
        if (wl == lane) {
            if (sl == 0)      val0 = -INFINITY;
            else if (sl == 1) val1 = -INFINITY;
            else              val2 = -INFINITY;
        }
    }

    // Fetch the 10 winners' qos values in ONE 10-lane load (independent lines).
    float myval = 0.0f; int myv = -1;
#pragma unroll
    for (int k = 0; k < K_TOP; ++k)
        if (lane == k) { myv = wk[k]; myval = wv[k]; }

    float c = 0.0f;
    if (myv >= 0) {
        const float rv = qos[((size_t)t * U_DIM + (size_t)myv) * I_DIM + i];
        const float av = arow[myv];
        c = myval * (rv - av);    // identical arithmetic to proven con[]
    }

    // wsum in ascending-k order -> bit-identical to the proven sequential sum.
    float wsum = 0.0f;
#pragma unroll
    for (int k = 0; k < K_TOP; ++k)
        wsum += __shfl(c, k, 64);

    if (lane == 0)
        out[b] = arow[u] + wsum / (ssum + 1e-8f);
}

// ---------------------------------------------------------------------------
// Fallback (proven round-0 baseline): used only if workspace is too small.
// ---------------------------------------------------------------------------
__global__ __launch_bounds__(256) void ucf_kernel(
    const float* __restrict__ qos,
    const float* __restrict__ user_avg,
    const float* __restrict__ user_sim,
    const int*   __restrict__ user_id,
    const int*   __restrict__ item_id,
    const int*   __restrict__ time_id,
    float*       __restrict__ out)
{
    const int lane = threadIdx.x & 63;
    const int wid  = threadIdx.x >> 6;
    const int b    = blockIdx.x * 4 + wid;
    if (b >= B_DIM) return;

    const int u = user_id[b];
    const int i = item_id[b];
    const int t = time_id[b];

    const float* qcol = qos + ((size_t)t * U_DIM) * (size_t)I_DIM + i;
    const float* srow = user_sim + (size_t)u * U_DIM;
    const float* arow = user_avg + (size_t)t * U_DIM;

    float val[3];
    float con[3];
#pragma unroll
    for (int j = 0; j < 3; ++j) {
        const int v = lane + j * 64;
        float sv = -INFINITY;
        float cv = 0.0f;
        if (v < U_DIM) {
            const float rv = qcol[(size_t)v * I_DIM];
            const float av = arow[v];
            const float s  = srow[v];
            sv = (rv > 0.0f) ? s : 0.0f;
            cv = sv * (rv - av);
        }
        val[j] = sv;
        con[j] = cv;
    }

    float ssum = 0.0f, wsum = 0.0f;
#pragma unroll
    for (int k = 0; k < K_TOP; ++k) {
        float mv = val[0]; float mc = con[0]; int mk = lane;
        if (val[1] > mv) { mv = val[1]; mc = con[1]; mk = lane + 64; }
        if (val[2] > mv) { mv = val[2]; mc = con[2]; mk = lane + 128; }
#pragma unroll
        for (int off = 32; off > 0; off >>= 1) {
            const float ov = __shfl_xor(mv, off, 64);
            const float oc = __shfl_xor(mc, off, 64);
            const int   ok = __shfl_xor(mk, off, 64);
            if (ov > mv || (ov == mv && ok < mk)) { mv = ov; mc = oc; mk = ok; }
        }
        ssum += mv;
        wsum += mc;
        if ((mk & 63) == lane) {
            const int slot = mk >> 6;
            if (slot == 0)      val[0] = -INFINITY;
            else if (slot == 1) val[1] = -INFINITY;
            else                val[2] = -INFINITY;
        }
    }

    if (lane == 0) {
        out[b] = arow[u] + wsum / (ssum + 1e-8f);
    }
}

extern "C" void kernel_launch(void* const* d_in, const int* in_sizes, int n_in,
                              void* d_out, int out_size, void* d_ws, size_t ws_size,
                              hipStream_t stream) {
    const float* qos  = (const float*)d_in[0];
    const float* uavg = (const float*)d_in[1];
    const float* usim = (const float*)d_in[2];
    const int*   uid  = (const int*)d_in[3];
    const int*   iid  = (const int*)d_in[4];
    const int*   tid  = (const int*)d_in[5];
    // d_in[6] is top_k, fixed at 10 by the problem instance (K_TOP).
    float* out = (float*)d_out;

    if (d_ws != nullptr && ws_size >= WS_BYTES) {
        unsigned* mask = (unsigned*)d_ws;
        // 64 t * 18 chunks * 5 words = 5760 waves = 1440 blocks
        build_mask<<<dim3(T_DIM * NCH * NWPC / 4), dim3(256), 0, stream>>>(qos, mask);
        ucf_select<<<dim3(B_DIM / 4), dim3(256), 0, stream>>>(
            qos, uavg, usim, uid, iid, tid, mask, out);
    } else {
        ucf_kernel<<<dim3(B_DIM / 4), dim3(256), 0, stream>>>(
            qos, uavg, usim, uid, iid, tid, out);
    }
}